// Round 2
// baseline (13352.336 us; speedup 1.0000x reference)
//
#include <hip/hip_runtime.h>
#include <cstdint>
#include <cstddef>

#define NENV 4096
#define SEQ  128
#define LATENT 64
#define EMB  256
#define HID  1024
#define SA   2

typedef _Float16 half8 __attribute__((ext_vector_type(8)));
typedef float f32x16 __attribute__((ext_vector_type(16)));

__device__ __forceinline__ float sigmoid_f(float x){ return 1.0f/(1.0f + __expf(-x)); }

__device__ __forceinline__ void dma16(const void* g, void* l){
  __builtin_amdgcn_global_load_lds(
      (const __attribute__((address_space(1))) void*)g,
      (__attribute__((address_space(3))) void*)l, 16, 0, 0);
}

__device__ __forceinline__ f32x16 mfma32(half8 a, half8 b, f32x16 c){
  return __builtin_amdgcn_mfma_f32_32x32x16_f16(a, b, c, 0, 0, 0);
}

// ---------- pre-pass: transpose + fp32->fp16 convert: in [K][C] -> out [C][K] ----------
__global__ void transpose_cvt_kernel(const float* __restrict__ in, _Float16* __restrict__ out,
                                     int K, int C){
  int n = K*C;
  for (int i = blockIdx.x*blockDim.x + threadIdx.x; i < n; i += gridDim.x*blockDim.x){
    int c = i / K;
    int k = i - c*K;
    out[i] = (_Float16)in[(size_t)k*C + c];
  }
}

__global__ void init_h_kernel(const float* __restrict__ rnn, float* __restrict__ h32,
                              _Float16* __restrict__ h16){
  int n = NENV*HID;
  for (int i = blockIdx.x*blockDim.x + threadIdx.x; i < n; i += gridDim.x*blockDim.x){
    float v = rnn[i];
    h32[i] = v;
    h16[i] = (_Float16)v;
  }
}

// ---------- fused GRU, 32x32x16 MFMA, global_load_lds staging ----------
// Block: 256 thr (4 waves), tile 128 rows x 64 h-cols x 3 gates. BK=32.
// LDS: A [kc(4)][row(128)] half8 slots 0..511; B [gate(3)][kc(4)][col(64)] slots 512..1279.
__device__ __forceinline__ void gru_phase(
    const _Float16* __restrict__ Ap, const _Float16* __restrict__ Wp, int K,
    int r0, int c0, int tid, int wave, int lane, int rbase, int cbase,
    half8* smem, f32x16* accR, f32x16* accZ, f32x16* accN)
{
  const int l31 = lane & 31, lhi = lane >> 5;
  const _Float16* g0; const _Float16* g1; const _Float16* g2; const _Float16* g3; const _Float16* g4;
  { int slot = tid;        int kc = slot >> 7, row = slot & 127;
    g0 = Ap + (size_t)(r0 + row)*K + kc*8; }
  { int slot = 256 + tid;  int kc = slot >> 7, row = slot & 127;
    g1 = Ap + (size_t)(r0 + row)*K + kc*8; }
  { int s2 = tid;          int gate = s2 >> 8, kc = (s2 >> 6) & 3, col = s2 & 63;
    g2 = Wp + (size_t)(gate*HID + c0 + col)*K + kc*8; }
  { int s2 = 256 + tid;    int gate = s2 >> 8, kc = (s2 >> 6) & 3, col = s2 & 63;
    g3 = Wp + (size_t)(gate*HID + c0 + col)*K + kc*8; }
  { int s2 = 512 + tid;    int gate = s2 >> 8, kc = (s2 >> 6) & 3, col = s2 & 63;
    g4 = Wp + (size_t)(gate*HID + c0 + col)*K + kc*8; }
  char* lbase = (char*)smem;
  char* l0 = lbase + (size_t)(0*256 + wave*64)*16;
  char* l1 = lbase + (size_t)(1*256 + wave*64)*16;
  char* l2 = lbase + (size_t)(2*256 + wave*64)*16;
  char* l3 = lbase + (size_t)(3*256 + wave*64)*16;
  char* l4 = lbase + (size_t)(4*256 + wave*64)*16;

  for (int k0 = 0; k0 < K; k0 += 32){
    dma16(g0, l0); dma16(g1, l1); dma16(g2, l2); dma16(g3, l3); dma16(g4, l4);
    g0 += 32; g1 += 32; g2 += 32; g3 += 32; g4 += 32;
    __syncthreads();
#pragma unroll
    for (int c = 0; c < 2; ++c){
      const int kc = c*2 + lhi;
      half8 a0 = smem[kc*128 + rbase      + l31];
      half8 a1 = smem[kc*128 + rbase + 32 + l31];
      half8 b0 = smem[512 +        kc*64 + cbase + l31];
      half8 b1 = smem[512 + 256 +  kc*64 + cbase + l31];
      half8 b2 = smem[512 + 512 +  kc*64 + cbase + l31];
      accR[0] = mfma32(a0, b0, accR[0]);
      accR[1] = mfma32(a1, b0, accR[1]);
      accZ[0] = mfma32(a0, b1, accZ[0]);
      accZ[1] = mfma32(a1, b1, accZ[1]);
      accN[0] = mfma32(a0, b2, accN[0]);
      accN[1] = mfma32(a1, b2, accN[1]);
    }
    __syncthreads();
  }
}

__global__ __launch_bounds__(256, 2) void gru_kernel(
    const _Float16* __restrict__ x2h, const _Float16* __restrict__ hcur,
    const _Float16* __restrict__ wihT, const _Float16* __restrict__ whhT,
    const float* __restrict__ bih, const float* __restrict__ bhh,
    float* __restrict__ h32, _Float16* __restrict__ hnxt)
{
  __shared__ half8 smem[1280];   // 20 KB
  const int tid = threadIdx.x;
  const int lane = tid & 63, wave = tid >> 6;
  // XCD swizzle: each XCD owns 2 col-groups so its W slice stays L2-resident
  const int id = blockIdx.x;
  const int xcd = id & 7, slot = id >> 3;
  const int colg = xcd*2 + (slot & 1);
  const int rowg = slot >> 1;
  const int r0 = rowg*128, c0 = colg*64;
  const int rbase = (wave & 1)*64, cbase = (wave >> 1)*32;
  const int l31 = lane & 31, lhi = lane >> 5;

  f32x16 accR[2], accZ[2], accN1[2], accN2[2];
#pragma unroll
  for (int i = 0; i < 16; ++i){
    accR[0][i]=0.f; accR[1][i]=0.f; accZ[0][i]=0.f; accZ[1][i]=0.f;
    accN1[0][i]=0.f; accN1[1][i]=0.f; accN2[0][i]=0.f; accN2[1][i]=0.f;
  }

  gru_phase(x2h,  wihT, EMB, r0, c0, tid, wave, lane, rbase, cbase, smem, accR, accZ, accN1);
  gru_phase(hcur, whhT, HID, r0, c0, tid, wave, lane, rbase, cbase, smem, accR, accZ, accN2);

  const int gc = c0 + cbase + l31;
  const float b_r  = bih[gc]         + bhh[gc];
  const float b_z  = bih[gc + HID]   + bhh[gc + HID];
  const float b_in = bih[gc + 2*HID];
  const float b_hn = bhh[gc + 2*HID];
#pragma unroll
  for (int rt = 0; rt < 2; ++rt){
#pragma unroll
    for (int reg = 0; reg < 16; ++reg){
      int row = r0 + rbase + rt*32 + (reg & 3) + 8*(reg >> 2) + 4*lhi;
      float rr = sigmoid_f(accR[rt][reg] + b_r);
      float u  = sigmoid_f(accZ[rt][reg] + b_z);
      float nn = tanhf(accN1[rt][reg] + b_in + rr*(accN2[rt][reg] + b_hn));
      size_t idx = (size_t)row*HID + gc;
      float hold = h32[idx];
      float hnew = (1.0f - u)*nn + u*hold;
      h32[idx] = hnew;
      hnxt[idx] = (_Float16)hnew;
    }
  }
}

// ---------- o1 = relu(h @ w3 + b3) fp16 out, 32x32x16 + DMA ----------
// Block: 256 thr, tile 128 rows x 64 cols. LDS: A 512 slots + B [kc(4)][col(64)] 256 slots.
__global__ __launch_bounds__(256, 2) void out1_kernel(
    const _Float16* __restrict__ h16, const _Float16* __restrict__ w3T,
    const float* __restrict__ b3, _Float16* __restrict__ o1)
{
  __shared__ half8 smem[768];    // 12 KB
  const int tid = threadIdx.x;
  const int lane = tid & 63, wave = tid >> 6;
  const int id = blockIdx.x;
  const int colg = id & 7;       // 8 col-groups of 64 over 512
  const int rowg = id >> 3;      // 32 row-groups of 128
  const int r0 = rowg*128, c0 = colg*64;
  const int rbase = (wave & 1)*64, cbase = (wave >> 1)*32;
  const int l31 = lane & 31, lhi = lane >> 5;

  f32x16 acc[2];
#pragma unroll
  for (int i = 0; i < 16; ++i){ acc[0][i]=0.f; acc[1][i]=0.f; }

  const _Float16* g0; const _Float16* g1; const _Float16* g2;
  { int slot = tid;       int kc = slot >> 7, row = slot & 127;
    g0 = h16 + (size_t)(r0 + row)*HID + kc*8; }
  { int slot = 256 + tid; int kc = slot >> 7, row = slot & 127;
    g1 = h16 + (size_t)(r0 + row)*HID + kc*8; }
  { int kc = tid >> 6, col = tid & 63;
    g2 = w3T + (size_t)(c0 + col)*HID + kc*8; }
  char* lbase = (char*)smem;
  char* l0 = lbase + (size_t)(0*256 + wave*64)*16;
  char* l1 = lbase + (size_t)(1*256 + wave*64)*16;
  char* l2 = lbase + (size_t)(2*256 + wave*64)*16;

  for (int k0 = 0; k0 < HID; k0 += 32){
    dma16(g0, l0); dma16(g1, l1); dma16(g2, l2);
    g0 += 32; g1 += 32; g2 += 32;
    __syncthreads();
#pragma unroll
    for (int c = 0; c < 2; ++c){
      const int kc = c*2 + lhi;
      half8 a0 = smem[kc*128 + rbase      + l31];
      half8 a1 = smem[kc*128 + rbase + 32 + l31];
      half8 b  = smem[512 + kc*64 + cbase + l31];
      acc[0] = mfma32(a0, b, acc[0]);
      acc[1] = mfma32(a1, b, acc[1]);
    }
    __syncthreads();
  }

  const int gc = c0 + cbase + l31;
  const float bb = b3[gc];
#pragma unroll
  for (int rt = 0; rt < 2; ++rt){
#pragma unroll
    for (int reg = 0; reg < 16; ++reg){
      int row = r0 + rbase + rt*32 + (reg & 3) + 8*(reg >> 2) + 4*lhi;
      o1[(size_t)row*(HID/2) + gc] = (_Float16)fmaxf(acc[rt][reg] + bb, 0.f);
    }
  }
}

// ---------- tail of step t fused with head of step t+1 ----------
// mode 0: init (state=-2, x2 for t=0); mode 1: mid; mode 2: last (head only)
__global__ void tail_head_kernel(
    const _Float16* __restrict__ o1, const float* __restrict__ w4, const float* __restrict__ b4,
    const float* __restrict__ z,  const float* __restrict__ w1, const float* __restrict__ b1,
    const float* __restrict__ w2, const float* __restrict__ b2,
    _Float16* __restrict__ x2h, float* __restrict__ out, int t, int mode)
{
  __shared__ float sw2[32*256];   // 32 KB
  __shared__ float sw1[66*32];    // 8.4 KB
  __shared__ float sz[16][64];
  __shared__ float sx1[16][32];
  __shared__ float sst[16][2];
  const int tid = threadIdx.x;
  const int r0 = blockIdx.x*16;

  if (mode != 2){
    for (int i = tid; i < 66*32; i += 256) sw1[i] = w1[i];
    for (int i = tid; i < 32*256; i += 256) sw2[i] = w2[i];
    int zt = (mode == 0) ? 0 : (t + 1);
    for (int i = tid; i < 16*64; i += 256){
      int r = i >> 6, k = i & 63;
      sz[r][k] = z[(size_t)(r0 + r)*SEQ*LATENT + zt*LATENT + k];
    }
  }

  if (mode != 0){
    int r = tid >> 4, p = tid & 15;
    const _Float16* orow = o1 + (size_t)(r0 + r)*(HID/2);
    float a0 = 0.f, a1 = 0.f;
    for (int k = p*32; k < p*32 + 32; ++k){
      float v = (float)orow[k];
      a0 += v*w4[k*2];
      a1 += v*w4[k*2 + 1];
    }
#pragma unroll
    for (int off = 1; off < 16; off <<= 1){
      a0 += __shfl_xor(a0, off);
      a1 += __shfl_xor(a1, off);
    }
    if (p == 0){
      a0 = tanhf(a0 + b4[0]);
      a1 = tanhf(a1 + b4[1]);
      out[(size_t)(r0 + r)*SEQ*SA + t*SA + 0] = a0;
      out[(size_t)(r0 + r)*SEQ*SA + t*SA + 1] = a1;
      sst[r][0] = a0; sst[r][1] = a1;
    }
  } else {
    if (tid < 32) sst[tid >> 1][tid & 1] = -2.0f;
  }
  __syncthreads();

  if (mode != 2){
    for (int it = tid; it < 16*32; it += 256){
      int r = it >> 5, j = it & 31;
      float acc = b1[j];
      acc += sst[r][0]*sw1[0*32 + j] + sst[r][1]*sw1[1*32 + j];
#pragma unroll 8
      for (int k = 0; k < 64; ++k) acc += sz[r][k]*sw1[(k + 2)*32 + j];
      sx1[r][j] = fmaxf(acc, 0.f);
    }
    __syncthreads();
    int col = tid;
    for (int r = 0; r < 16; ++r){
      float acc = b2[col];
#pragma unroll
      for (int k = 0; k < 32; ++k) acc += sx1[r][k]*sw2[k*256 + col];
      x2h[(size_t)(r0 + r)*EMB + col] = (_Float16)fmaxf(acc, 0.f);
    }
  }
}

extern "C" void kernel_launch(void* const* d_in, const int* in_sizes, int n_in,
                              void* d_out, int out_size, void* d_ws, size_t ws_size,
                              hipStream_t stream) {
  const float* z   = (const float*)d_in[0];
  const float* rnn = (const float*)d_in[1];
  const float* w1  = (const float*)d_in[2];
  const float* b1  = (const float*)d_in[3];
  const float* w2  = (const float*)d_in[4];
  const float* b2  = (const float*)d_in[5];
  const float* wih = (const float*)d_in[6];
  const float* bih = (const float*)d_in[7];
  const float* whh = (const float*)d_in[8];
  const float* bhh = (const float*)d_in[9];
  const float* w3  = (const float*)d_in[10];
  const float* b3  = (const float*)d_in[11];
  const float* w4  = (const float*)d_in[12];
  const float* b4  = (const float*)d_in[13];
  float* out = (float*)d_out;

  char* ws = (char*)d_ws;
  _Float16* wihT = (_Float16*)ws;                 ws += (size_t)3*HID*EMB*2;
  _Float16* whhT = (_Float16*)ws;                 ws += (size_t)3*HID*HID*2;
  _Float16* w3T  = (_Float16*)ws;                 ws += (size_t)(HID/2)*HID*2;
  _Float16* h16a = (_Float16*)ws;                 ws += (size_t)NENV*HID*2;
  _Float16* h16b = (_Float16*)ws;                 ws += (size_t)NENV*HID*2;
  float*    h32  = (float*)ws;                    ws += (size_t)NENV*HID*4;
  _Float16* x2h  = (_Float16*)ws;                 ws += (size_t)NENV*EMB*2;
  _Float16* o1   = (_Float16*)ws;                 ws += (size_t)NENV*(HID/2)*2;

  transpose_cvt_kernel<<<512, 256, 0, stream>>>(wih, wihT, EMB, 3*HID);
  transpose_cvt_kernel<<<1024, 256, 0, stream>>>(whh, whhT, HID, 3*HID);
  transpose_cvt_kernel<<<256, 256, 0, stream>>>(w3, w3T, HID, HID/2);
  init_h_kernel<<<1024, 256, 0, stream>>>(rnn, h32, h16a);

  tail_head_kernel<<<NENV/16, 256, 0, stream>>>(o1, w4, b4, z, w1, b1, w2, b2, x2h, out, 0, 0);

  for (int t = 0; t < SEQ; ++t){
    _Float16* hc = (t & 1) ? h16b : h16a;
    _Float16* hn = (t & 1) ? h16a : h16b;
    gru_kernel<<<512, 256, 0, stream>>>(x2h, hc, wihT, whhT, bih, bhh, h32, hn);
    out1_kernel<<<256, 256, 0, stream>>>(hn, w3T, b3, o1);
    tail_head_kernel<<<NENV/16, 256, 0, stream>>>(o1, w4, b4, z, w1, b1, w2, b2, x2h, out,
                                                  t, (t < SEQ - 1) ? 1 : 2);
  }

  hipMemcpyAsync(out + (size_t)NENV*SEQ*SA, h32, (size_t)NENV*HID*sizeof(float),
                 hipMemcpyDeviceToDevice, stream);
}

// Round 3
// 10898.478 us; speedup vs baseline: 1.2252x; 1.2252x over previous
//
#include <hip/hip_runtime.h>
#include <cstdint>
#include <cstddef>

#define NENV 4096
#define SEQ  128
#define LATENT 64
#define EMB  256
#define HID  1024
#define SA   2

typedef _Float16 half8 __attribute__((ext_vector_type(8)));
typedef float f32x4 __attribute__((ext_vector_type(4)));

__device__ __forceinline__ float sigmoid_f(float x){ return 1.0f/(1.0f + __expf(-x)); }

__device__ __forceinline__ void dma16(const void* g, void* l){
  __builtin_amdgcn_global_load_lds(
      (const __attribute__((address_space(1))) void*)g,
      (__attribute__((address_space(3))) void*)l, 16, 0, 0);
}

__device__ __forceinline__ f32x4 mfma16(half8 a, half8 b, f32x4 c){
  return __builtin_amdgcn_mfma_f32_16x16x32_f16(a, b, c, 0, 0, 0);
}

// ---------- pre-pass: transpose + fp32->fp16: in [K][C] -> out [C][K] ----------
__global__ void transpose_cvt_kernel(const float* __restrict__ in, _Float16* __restrict__ out,
                                     int K, int C){
  int n = K*C;
  for (int i = blockIdx.x*blockDim.x + threadIdx.x; i < n; i += gridDim.x*blockDim.x){
    int c = i / K;
    int k = i - c*K;
    out[i] = (_Float16)in[(size_t)k*C + c];
  }
}

__global__ void init_h_kernel(const float* __restrict__ rnn, _Float16* __restrict__ h16){
  int n = NENV*HID;
  for (int i = blockIdx.x*blockDim.x + threadIdx.x; i < n; i += gridDim.x*blockDim.x){
    h16[i] = (_Float16)rnn[i];
  }
}

// ---------- fused GRU: 64 rows x 64 h-cols x 3 gates, 16x16x32 MFMA, DMA staging ----------
// LDS: sA[256] half8 = A[row(64)][seg(4)]; sB[g][256] = W^T[col(64)][seg(4)].
// DMA slot tid -> row = tid>>2, seg = tid&3; wave-uniform LDS base = slot wave*64.
__global__ __launch_bounds__(256, 4) void gru_kernel(
    const _Float16* __restrict__ x2h, const _Float16* __restrict__ hcur,
    const _Float16* __restrict__ wihT, const _Float16* __restrict__ whhT,
    const float* __restrict__ bih, const float* __restrict__ bhh,
    _Float16* __restrict__ hnxt, float* __restrict__ hout)
{
  __shared__ half8 sA[256];
  __shared__ half8 sB[3][256];
  const int tid = threadIdx.x;
  const int lane = tid & 63, wave = tid >> 6;
  const int m = lane & 15, q = lane >> 4, n0 = wave*16;
  const int row = tid >> 2, seg = tid & 3;

  // XCD swizzle: blocks with id%8==x land on XCD x; give each XCD 2 col-groups
  const int id = blockIdx.x;
  const int colg = (id & 7)*2 + ((id >> 3) & 1);
  const int rowg = id >> 4;
  const int r0 = rowg*64, c0 = colg*64;

  f32x4 accR[4], accZ[4], accNi[4], accNh[4];
#pragma unroll
  for (int i = 0; i < 4; ++i){
    accR[i] = (f32x4){0.f,0.f,0.f,0.f};
    accZ[i] = (f32x4){0.f,0.f,0.f,0.f};
    accNi[i] = (f32x4){0.f,0.f,0.f,0.f};
    accNh[i] = (f32x4){0.f,0.f,0.f,0.f};
  }

  char* dA  = (char*)&sA[wave*64];
  char* dB0 = (char*)&sB[0][wave*64];
  char* dB1 = (char*)&sB[1][wave*64];
  char* dB2 = (char*)&sB[2][wave*64];

#pragma unroll
  for (int phase = 0; phase < 2; ++phase){
    const _Float16* A = phase ? hcur : x2h;
    const _Float16* W = phase ? whhT : wihT;
    const int K = phase ? HID : EMB;
    f32x4* accN = phase ? accNh : accNi;

    const _Float16* gA  = A + (size_t)(r0 + row)*K + seg*8;
    const _Float16* gB0 = W + (size_t)(0*HID + c0 + row)*K + seg*8;
    const _Float16* gB1 = W + (size_t)(1*HID + c0 + row)*K + seg*8;
    const _Float16* gB2 = W + (size_t)(2*HID + c0 + row)*K + seg*8;

    for (int k0 = 0; k0 < K; k0 += 32){
      dma16(gA, dA); dma16(gB0, dB0); dma16(gB1, dB1); dma16(gB2, dB2);
      gA += 32; gB0 += 32; gB1 += 32; gB2 += 32;
      __syncthreads();   // drains vmcnt -> DMA data visible
      half8 b0 = sB[0][(n0+m)*4 + q];
      half8 b1 = sB[1][(n0+m)*4 + q];
      half8 b2 = sB[2][(n0+m)*4 + q];
#pragma unroll
      for (int mt = 0; mt < 4; ++mt){
        half8 a = sA[(mt*16 + m)*4 + q];
        accR[mt] = mfma16(a, b0, accR[mt]);
        accZ[mt] = mfma16(a, b1, accZ[mt]);
        accN[mt] = mfma16(a, b2, accN[mt]);
      }
      __syncthreads();   // all reads done before next overwrite
    }
  }

  const int gc = c0 + n0 + m;
  const float b_r  = bih[gc]         + bhh[gc];
  const float b_z  = bih[gc + HID]   + bhh[gc + HID];
  const float b_in = bih[gc + 2*HID];
  const float b_hn = bhh[gc + 2*HID];
#pragma unroll
  for (int mt = 0; mt < 4; ++mt){
#pragma unroll
    for (int r = 0; r < 4; ++r){
      int grow = r0 + mt*16 + q*4 + r;
      float rr = sigmoid_f(accR[mt][r] + b_r);
      float u  = sigmoid_f(accZ[mt][r] + b_z);
      float nn = tanhf(accNi[mt][r] + b_in + rr*(accNh[mt][r] + b_hn));
      size_t idx = (size_t)grow*HID + gc;
      float hold = (float)hcur[idx];
      float hnew = (1.0f - u)*nn + u*hold;
      hnxt[idx] = (_Float16)hnew;
      if (hout) hout[idx] = hnew;
    }
  }
}

// ---------- o1 = relu(h @ w3 + b3) -> fp16, 64x64 tile, DMA staging ----------
__global__ __launch_bounds__(256, 4) void out1_kernel(
    const _Float16* __restrict__ h16, const _Float16* __restrict__ w3T,
    const float* __restrict__ b3, _Float16* __restrict__ o1)
{
  __shared__ half8 sA[256];
  __shared__ half8 sB[256];
  const int tid = threadIdx.x;
  const int lane = tid & 63, wave = tid >> 6;
  const int m = lane & 15, q = lane >> 4, n0 = wave*16;
  const int row = tid >> 2, seg = tid & 3;

  const int id = blockIdx.x;
  const int colg = id & 7;     // 8 col-groups of 64 over 512; XCD x owns colg x
  const int rowg = id >> 3;    // 64 row-groups
  const int r0 = rowg*64, c0 = colg*64;

  f32x4 acc[4];
#pragma unroll
  for (int i = 0; i < 4; ++i) acc[i] = (f32x4){0.f,0.f,0.f,0.f};

  char* dA = (char*)&sA[wave*64];
  char* dB = (char*)&sB[wave*64];
  const _Float16* gA = h16 + (size_t)(r0 + row)*HID + seg*8;
  const _Float16* gB = w3T + (size_t)(c0 + row)*HID + seg*8;

  for (int k0 = 0; k0 < HID; k0 += 32){
    dma16(gA, dA); dma16(gB, dB);
    gA += 32; gB += 32;
    __syncthreads();
    half8 b = sB[(n0+m)*4 + q];
#pragma unroll
    for (int mt = 0; mt < 4; ++mt){
      half8 a = sA[(mt*16 + m)*4 + q];
      acc[mt] = mfma16(a, b, acc[mt]);
    }
    __syncthreads();
  }

  const int gc = c0 + n0 + m;
  const float bb = b3[gc];
#pragma unroll
  for (int mt = 0; mt < 4; ++mt){
#pragma unroll
    for (int r = 0; r < 4; ++r){
      int grow = r0 + mt*16 + q*4 + r;
      o1[(size_t)grow*(HID/2) + gc] = (_Float16)fmaxf(acc[mt][r] + bb, 0.f);
    }
  }
}

// ---------- tail of step t fused with head of step t+1 ----------
// mode 0: init (state=-2, x2 for t=0); mode 1: mid; mode 2: last (head only)
__global__ void tail_head_kernel(
    const _Float16* __restrict__ o1, const float* __restrict__ w4, const float* __restrict__ b4,
    const float* __restrict__ z,  const float* __restrict__ w1, const float* __restrict__ b1,
    const float* __restrict__ w2, const float* __restrict__ b2,
    _Float16* __restrict__ x2h, float* __restrict__ out, int t, int mode)
{
  __shared__ float sw2[32*256];   // 32 KB
  __shared__ float sw1[66*32];    // 8.4 KB
  __shared__ float sz[16][64];
  __shared__ float sx1[16][32];
  __shared__ float sst[16][2];
  const int tid = threadIdx.x;
  const int r0 = blockIdx.x*16;

  if (mode != 2){
    for (int i = tid; i < 66*32; i += 256) sw1[i] = w1[i];
    for (int i = tid; i < 32*256; i += 256) sw2[i] = w2[i];
    int zt = (mode == 0) ? 0 : (t + 1);
    for (int i = tid; i < 16*64; i += 256){
      int r = i >> 6, k = i & 63;
      sz[r][k] = z[(size_t)(r0 + r)*SEQ*LATENT + zt*LATENT + k];
    }
  }

  if (mode != 0){
    int r = tid >> 4, p = tid & 15;
    const _Float16* orow = o1 + (size_t)(r0 + r)*(HID/2);
    float a0 = 0.f, a1 = 0.f;
    for (int k = p*32; k < p*32 + 32; ++k){
      float v = (float)orow[k];
      a0 += v*w4[k*2];
      a1 += v*w4[k*2 + 1];
    }
#pragma unroll
    for (int off = 1; off < 16; off <<= 1){
      a0 += __shfl_xor(a0, off);
      a1 += __shfl_xor(a1, off);
    }
    if (p == 0){
      a0 = tanhf(a0 + b4[0]);
      a1 = tanhf(a1 + b4[1]);
      out[(size_t)(r0 + r)*SEQ*SA + t*SA + 0] = a0;
      out[(size_t)(r0 + r)*SEQ*SA + t*SA + 1] = a1;
      sst[r][0] = a0; sst[r][1] = a1;
    }
  } else {
    if (tid < 32) sst[tid >> 1][tid & 1] = -2.0f;
  }
  __syncthreads();

  if (mode != 2){
    for (int it = tid; it < 16*32; it += 256){
      int r = it >> 5, j = it & 31;
      float acc = b1[j];
      acc += sst[r][0]*sw1[0*32 + j] + sst[r][1]*sw1[1*32 + j];
#pragma unroll 8
      for (int k = 0; k < 64; ++k) acc += sz[r][k]*sw1[(k + 2)*32 + j];
      sx1[r][j] = fmaxf(acc, 0.f);
    }
    __syncthreads();
    int col = tid;
    for (int r = 0; r < 16; ++r){
      float acc = b2[col];
#pragma unroll
      for (int k = 0; k < 32; ++k) acc += sx1[r][k]*sw2[k*256 + col];
      x2h[(size_t)(r0 + r)*EMB + col] = (_Float16)fmaxf(acc, 0.f);
    }
  }
}

extern "C" void kernel_launch(void* const* d_in, const int* in_sizes, int n_in,
                              void* d_out, int out_size, void* d_ws, size_t ws_size,
                              hipStream_t stream) {
  const float* z   = (const float*)d_in[0];
  const float* rnn = (const float*)d_in[1];
  const float* w1  = (const float*)d_in[2];
  const float* b1  = (const float*)d_in[3];
  const float* w2  = (const float*)d_in[4];
  const float* b2  = (const float*)d_in[5];
  const float* wih = (const float*)d_in[6];
  const float* bih = (const float*)d_in[7];
  const float* whh = (const float*)d_in[8];
  const float* bhh = (const float*)d_in[9];
  const float* w3  = (const float*)d_in[10];
  const float* b3  = (const float*)d_in[11];
  const float* w4  = (const float*)d_in[12];
  const float* b4  = (const float*)d_in[13];
  float* out = (float*)d_out;

  char* ws = (char*)d_ws;
  _Float16* wihT = (_Float16*)ws;                 ws += (size_t)3*HID*EMB*2;
  _Float16* whhT = (_Float16*)ws;                 ws += (size_t)3*HID*HID*2;
  _Float16* w3T  = (_Float16*)ws;                 ws += (size_t)(HID/2)*HID*2;
  _Float16* h16a = (_Float16*)ws;                 ws += (size_t)NENV*HID*2;
  _Float16* h16b = (_Float16*)ws;                 ws += (size_t)NENV*HID*2;
  _Float16* x2h  = (_Float16*)ws;                 ws += (size_t)NENV*EMB*2;
  _Float16* o1   = (_Float16*)ws;                 ws += (size_t)NENV*(HID/2)*2;

  transpose_cvt_kernel<<<512, 256, 0, stream>>>(wih, wihT, EMB, 3*HID);
  transpose_cvt_kernel<<<1024, 256, 0, stream>>>(whh, whhT, HID, 3*HID);
  transpose_cvt_kernel<<<256, 256, 0, stream>>>(w3, w3T, HID, HID/2);
  init_h_kernel<<<1024, 256, 0, stream>>>(rnn, h16a);

  tail_head_kernel<<<NENV/16, 256, 0, stream>>>(o1, w4, b4, z, w1, b1, w2, b2, x2h, out, 0, 0);

  float* hfinal = out + (size_t)NENV*SEQ*SA;
  for (int t = 0; t < SEQ; ++t){
    _Float16* hc = (t & 1) ? h16b : h16a;
    _Float16* hn = (t & 1) ? h16a : h16b;
    gru_kernel<<<1024, 256, 0, stream>>>(x2h, hc, wihT, whhT, bih, bhh, hn,
                                         (t == SEQ - 1) ? hfinal : nullptr);
    out1_kernel<<<512, 256, 0, stream>>>(hn, w3T, b3, o1);
    tail_head_kernel<<<NENV/16, 256, 0, stream>>>(o1, w4, b4, z, w1, b1, w2, b2, x2h, out,
                                                  t, (t < SEQ - 1) ? 1 : 2);
  }
}